// Round 13
// baseline (153.679 us; speedup 1.0000x reference)
//
#include <hip/hip_runtime.h>
#include <stdint.h>

typedef __attribute__((ext_vector_type(4))) int i32x4;

#define N_FRAMES 16386
#define D_DIM    1024
#define O_DIM    2048
#define L_CTX    3
#define K_DIM    3072   // D_DIM * L_CTX
#define T_DIM    16384  // N_FRAMES - L_CTX + 1
#define NKT      48     // K_DIM / 64  (64-byte K-tiles)

// workspace byte offsets
#define WS_PART   0u        // 512 x uint2 flipped {min,max} partials
#define WS_PARAMS 8192u
#define WS_CO     16384u    // O_DIM int32
#define WS_S      32768u    // N_FRAMES int32
#define WS_QW     262144u
#define WS_QX     8388608u

struct Params {
  float w_scale, in_scale, cscale;
  int   w_zp, in_zp, konst;
};

typedef __attribute__((address_space(3))) void       lds_void;
typedef const __attribute__((address_space(1))) void gbl_void;

__device__ __forceinline__ unsigned flip_f(float f) {
  unsigned u = __float_as_uint(f);
  return (u & 0x80000000u) ? ~u : (u | 0x80000000u);
}
__device__ __forceinline__ float unflip_f(unsigned v) {
  unsigned u = (v & 0x80000000u) ? (v ^ 0x80000000u) : ~v;
  return __uint_as_float(u);
}

// grid must be exactly 512 blocks; block b writes partials[b] = {min,max} (flipped)
__global__ __launch_bounds__(256) void wminmax_kernel(const float4* __restrict__ w,
                                                      uint2* __restrict__ part, int n4) {
  unsigned lmin = 0xFFFFFFFFu, lmax = 0u;
  for (int i = blockIdx.x * blockDim.x + threadIdx.x; i < n4; i += gridDim.x * blockDim.x) {
    float4 v = w[i];
    unsigned a = flip_f(v.x), b = flip_f(v.y), c = flip_f(v.z), d = flip_f(v.w);
    lmin = min(lmin, min(min(a, b), min(c, d)));
    lmax = max(lmax, max(max(a, b), max(c, d)));
  }
#pragma unroll
  for (int off = 32; off > 0; off >>= 1) {
    lmin = min(lmin, (unsigned)__shfl_xor((int)lmin, off, 64));
    lmax = max(lmax, (unsigned)__shfl_xor((int)lmax, off, 64));
  }
  __shared__ unsigned rmn[4], rmx[4];
  const int wv = threadIdx.x >> 6;
  if ((threadIdx.x & 63) == 0) { rmn[wv] = lmin; rmx[wv] = lmax; }
  __syncthreads();
  if (threadIdx.x == 0) {
    unsigned mn = min(min(rmn[0], rmn[1]), min(rmn[2], rmn[3]));
    unsigned mx = max(max(rmx[0], rmx[1]), max(rmx[2], rmx[3]));
    part[blockIdx.x] = make_uint2(mn, mx);
  }
}

// reduce 512 partials -> Params
__global__ __launch_bounds__(256) void params_kernel(const uint2* __restrict__ part,
                                                     const float* __restrict__ in_min,
                                                     const float* __restrict__ in_max,
                                                     Params* __restrict__ p) {
  const int t = threadIdx.x;
  uint2 a = part[t], b = part[t + 256];
  unsigned mn = min(a.x, b.x), mx = max(a.y, b.y);
#pragma unroll
  for (int off = 32; off > 0; off >>= 1) {
    mn = min(mn, (unsigned)__shfl_xor((int)mn, off, 64));
    mx = max(mx, (unsigned)__shfl_xor((int)mx, off, 64));
  }
  __shared__ unsigned rmn[4], rmx[4];
  const int wv = t >> 6;
  if ((t & 63) == 0) { rmn[wv] = mn; rmx[wv] = mx; }
  __syncthreads();
  if (t == 0) {
    float wmin = unflip_f(min(min(rmn[0], rmn[1]), min(rmn[2], rmn[3])));
    float wmax = unflip_f(max(max(rmx[0], rmx[1]), max(rmx[2], rmx[3])));
    float ws = (wmax - wmin) / 254.0f;
    float wz = -127.0f - wmin / ws;
    wz = fminf(fmaxf(wz, -127.0f), 127.0f);
    int wzp = (int)wz;  // trunc toward zero, matches jnp.trunc->int
    float imin = *in_min, imax = *in_max;
    float is = (imax - imin) / 254.0f;
    float iz = -127.0f - imin / is;
    iz = fminf(fmaxf(iz, -127.0f), 127.0f);
    int izp = (int)iz;
    p->w_scale = ws; p->in_scale = is; p->cscale = is * ws;
    p->w_zp = wzp;   p->in_zp = izp;
    p->konst = K_DIM * wzp * izp;
  }
}

__global__ __launch_bounds__(256) void quantw_kernel(
    const float* __restrict__ w, const float* __restrict__ bias,
    const Params* __restrict__ p, int8_t* __restrict__ qw,
    int* __restrict__ co, float* __restrict__ dq, float* __restrict__ bias_out) {
  const int o = blockIdx.x;
  const float ws = p->w_scale;
  const float zpf = (float)p->w_zp;
  const float* wrow = w + (size_t)o * K_DIM;
  float* dqrow = dq + (size_t)o * K_DIM;
  int8_t* qrow = qw + (size_t)o * K_DIM;
  int sum = 0;
#pragma unroll
  for (int pass = 0; pass < 3; ++pass) {
    const int k = (pass << 10) + (threadIdx.x << 2);
    float4 v = *(const float4*)(wrow + k);
    int8_t c0 = (int8_t)(int)rintf(v.x / ws + zpf);
    int8_t c1 = (int8_t)(int)rintf(v.y / ws + zpf);
    int8_t c2 = (int8_t)(int)rintf(v.z / ws + zpf);
    int8_t c3 = (int8_t)(int)rintf(v.w / ws + zpf);
    sum += (int)c0 + (int)c1 + (int)c2 + (int)c3;
    unsigned packed = (unsigned)(uint8_t)c0 | ((unsigned)(uint8_t)c1 << 8)
                    | ((unsigned)(uint8_t)c2 << 16) | ((unsigned)(uint8_t)c3 << 24);
    *(unsigned*)(qrow + k) = packed;
    float4 d;
    d.x = ((float)c0 - zpf) * ws;
    d.y = ((float)c1 - zpf) * ws;
    d.z = ((float)c2 - zpf) * ws;
    d.w = ((float)c3 - zpf) * ws;
    *(float4*)(dqrow + k) = d;
  }
  __shared__ int red[4];
#pragma unroll
  for (int off = 32; off > 0; off >>= 1) sum += __shfl_xor(sum, off, 64);
  if ((threadIdx.x & 63) == 0) red[threadIdx.x >> 6] = sum;
  __syncthreads();
  if (threadIdx.x == 0) {
    int tot = red[0] + red[1] + red[2] + red[3];
    co[o] = -p->in_zp * tot;
    bias_out[o] = bias[o];
  }
}

__global__ __launch_bounds__(256) void quantx_kernel(
    const float* __restrict__ x, const Params* __restrict__ p,
    int8_t* __restrict__ qx, int* __restrict__ s) {
  const int n = blockIdx.x;
  const float is = p->in_scale;
  const float zpf = (float)p->in_zp;
  const float4 v = *((const float4*)(x + (size_t)n * D_DIM) + threadIdx.x);
  int8_t c0 = (int8_t)(int)rintf(v.x / is + zpf);
  int8_t c1 = (int8_t)(int)rintf(v.y / is + zpf);
  int8_t c2 = (int8_t)(int)rintf(v.z / is + zpf);
  int8_t c3 = (int8_t)(int)rintf(v.w / is + zpf);
  unsigned packed = (unsigned)(uint8_t)c0 | ((unsigned)(uint8_t)c1 << 8)
                  | ((unsigned)(uint8_t)c2 << 16) | ((unsigned)(uint8_t)c3 << 24);
  ((unsigned*)(qx + (size_t)n * D_DIM))[threadIdx.x] = packed;
  int sum = (int)c0 + (int)c1 + (int)c2 + (int)c3;
  __shared__ int red[4];
#pragma unroll
  for (int off = 32; off > 0; off >>= 1) sum += __shfl_xor(sum, off, 64);
  if ((threadIdx.x & 63) == 0) red[threadIdx.x >> 6] = sum;
  __syncthreads();
  if (threadIdx.x == 0) s[n] = red[0] + red[1] + red[2] + red[3];
}

// int8 NT GEMM, 256x256 tile, 64B K-tiles, 8 waves (2x4, per-wave 128x64).
// TRIPLE-buffered LDS (3 x 32KB = 96KB): frags(kt+1) are certified one barrier
// early, so their ds_reads roll INSIDE the MFMA burst of tile kt (a[m] reloaded
// right after its 4 MFMAs; b[] reloaded after the burst). Dense 64B rows ->
// conflict-free reads/writes without swizzle. Per K-tile: 1 barrier + 1 vmcnt +
// 1 lgkm.  Ledger: stage(kt+2) -> LDS[(kt+2)%3] (held tile kt-1, reads certified
// at end-of-(kt-1) barrier); reads of frags(kt+1) from LDS[(kt+1)%3] (staging
// certified at same barrier); own vmcnt(0) + barrier at iter end certify
// stage(kt+2) for iter kt+1's rolling reads.
#define ITERX(KT, RB, SB)                                                      \
  {                                                                            \
    asm volatile("s_waitcnt lgkmcnt(0)" ::: "memory");                         \
    if ((KT) + 2 < NKT) stage(SB, (KT) + 2);                                   \
    __builtin_amdgcn_s_setprio(1);                                             \
    _Pragma("unroll")                                                          \
    for (int m = 0; m < 8; ++m) {                                              \
      _Pragma("unroll")                                                        \
      for (int n = 0; n < 4; ++n)                                              \
        acc[m][n] = __builtin_amdgcn_mfma_i32_16x16x64_i8(a[m], b[n], acc[m][n], 0, 0, 0); \
      if ((KT) + 1 < NKT)                                                      \
        a[m] = *(const i32x4*)&A_lds[RB][arow + (m << 10) + kgo];              \
    }                                                                          \
    __builtin_amdgcn_s_setprio(0);                                             \
    if ((KT) + 1 < NKT) {                                                      \
      _Pragma("unroll")                                                        \
      for (int n = 0; n < 4; ++n)                                              \
        b[n] = *(const i32x4*)&B_lds[RB][brow + (n << 10) + kgo];              \
      asm volatile("s_waitcnt vmcnt(0)" ::: "memory");                         \
      __builtin_amdgcn_s_barrier();                                            \
    }                                                                          \
  }

__global__ __launch_bounds__(512, 2) void gemm_kernel(
    const int8_t* __restrict__ qx, const int8_t* __restrict__ qw,
    const int* __restrict__ co, const int* __restrict__ s,
    const float* __restrict__ bias, const Params* __restrict__ p,
    float* __restrict__ out) {
  __shared__ int8_t A_lds[3][16384];   // [buf][row*64 + chunk*16], 256 rows
  __shared__ int8_t B_lds[3][16384];

  const int bid = blockIdx.x;
  const int tn = bid & 7;   // XCD-local n-tile: B panel L2-resident per XCD
  const int tm = bid >> 3;
  const int m0 = tm << 8, n0 = tn << 8;
  const int tid = threadIdx.x;
  const int lane = tid & 63, wave = tid >> 6;
  const int wm = wave >> 2, wn = wave & 3;   // 2x4 wave grid, per-wave 128x64
  const int lr = lane & 15, kg = lane >> 4;
  const int kgo = kg << 4;

  // staging: one wave-event = 64 lanes x 16B = 1KB = 16 rows x 64B; lane l ->
  // row l>>2, chunk l&3 (linear, dense -> no swizzle needed).
  const int8_t* qxa = qx + (size_t)(m0 + (lane >> 2)) * D_DIM + ((lane & 3) << 4);
  const int8_t* qwb = qw + (size_t)(n0 + (lane >> 2)) * K_DIM + ((lane & 3) << 4);

  // fragment reads: frag base = ((row base + lr) * 64); chunk kg*16 (dense 1KB)
  const int arow = ((wm << 7) + lr) << 6;
  const int brow = ((wn << 6) + lr) << 6;

  i32x4 a[8], b[4];
  i32x4 acc[8][4] = {};

  // stage tile kt into buffer sb: 2 A-events + 2 B-events per wave (4 gloads)
  auto stage = [&](int sb, int kt) {
#pragma unroll
    for (int e = 0; e < 2; ++e) {
      const int ev = (wave << 1) + e;   // 0..15, covers rows [ev*16, ev*16+16)
      __builtin_amdgcn_global_load_lds(
          (gbl_void*)(qxa + (size_t)(ev << 4) * D_DIM + (kt << 6)),
          (lds_void*)(&A_lds[sb][ev << 10]), 16, 0, 0);
      __builtin_amdgcn_global_load_lds(
          (gbl_void*)(qwb + (size_t)(ev << 4) * K_DIM + (kt << 6)),
          (lds_void*)(&B_lds[sb][ev << 10]), 16, 0, 0);
    }
  };

  // prologue: stage tiles 0,1; certify both; read frags(0)
  stage(0, 0);
  stage(1, 1);
  asm volatile("s_waitcnt vmcnt(0)" ::: "memory");
  __builtin_amdgcn_s_barrier();
#pragma unroll
  for (int m = 0; m < 8; ++m)
    a[m] = *(const i32x4*)&A_lds[0][arow + (m << 10) + kgo];
#pragma unroll
  for (int n = 0; n < 4; ++n)
    b[n] = *(const i32x4*)&B_lds[0][brow + (n << 10) + kgo];

  for (int kt = 0; kt < NKT; kt += 3) {
    ITERX(kt + 0, 1, 2);
    ITERX(kt + 1, 2, 0);
    ITERX(kt + 2, 0, 1);
  }

  // epilogue: dequant + zero-point correction (ct inline from s[]) + bias
  const float cscale = p->cscale;
  const int   wzp    = p->w_zp;
  const int   konst  = p->konst;
  int   cov[4];
  float bov[4];
#pragma unroll
  for (int n = 0; n < 4; ++n) {
    const int o_ = n0 + (wn << 6) + (n << 4) + lr;
    cov[n] = co[o_];
    bov[n] = bias[o_];
  }
#pragma unroll
  for (int m = 0; m < 8; ++m) {
    const int tbase = m0 + (wm << 7) + (m << 4) + (kg << 2);
    int sv[6];
#pragma unroll
    for (int r = 0; r < 6; ++r) sv[r] = s[tbase + r];
    int ctv[4];
#pragma unroll
    for (int r = 0; r < 4; ++r) ctv[r] = konst - wzp * (sv[r] + sv[r + 1] + sv[r + 2]);
#pragma unroll
    for (int n = 0; n < 4; ++n) {
      const int o_ = n0 + (wn << 6) + (n << 4) + lr;
#pragma unroll
      for (int r = 0; r < 4; ++r) {
        out[(size_t)(tbase + r) * O_DIM + o_] =
            (float)(acc[m][n][r] + cov[n] + ctv[r]) * cscale + bov[n];
      }
    }
  }
}

extern "C" void kernel_launch(void* const* d_in, const int* in_sizes, int n_in,
                              void* d_out, int out_size, void* d_ws, size_t ws_size,
                              hipStream_t stream) {
  const float* x      = (const float*)d_in[0];
  const float* w      = (const float*)d_in[1];
  const float* bias   = (const float*)d_in[2];
  const float* in_min = (const float*)d_in[3];
  const float* in_max = (const float*)d_in[4];
  float* out = (float*)d_out;

  uint8_t* ws = (uint8_t*)d_ws;
  uint2*    part = (uint2*)(ws + WS_PART);
  Params*   prm  = (Params*)(ws + WS_PARAMS);
  int*      co   = (int*)(ws + WS_CO);
  int*      s    = (int*)(ws + WS_S);
  int8_t*   qw   = (int8_t*)(ws + WS_QW);
  int8_t*   qx   = (int8_t*)(ws + WS_QX);

  float* dq_out   = out + (size_t)T_DIM * O_DIM;
  float* bias_out = dq_out + (size_t)O_DIM * K_DIM;

  wminmax_kernel<<<512, 256, 0, stream>>>((const float4*)w, part, O_DIM * K_DIM / 4);
  params_kernel<<<1, 256, 0, stream>>>(part, in_min, in_max, prm);
  quantw_kernel<<<O_DIM, 256, 0, stream>>>(w, bias, prm, qw, co, dq_out, bias_out);
  quantx_kernel<<<N_FRAMES, 256, 0, stream>>>(x, prm, qx, s);
  gemm_kernel<<<(T_DIM / 256) * (O_DIM / 256), 512, 0, stream>>>(qx, qw, co, s, bias, prm, out);
}

// Round 14
// 149.819 us; speedup vs baseline: 1.0258x; 1.0258x over previous
//
#include <hip/hip_runtime.h>
#include <stdint.h>

typedef __attribute__((ext_vector_type(4))) int i32x4;

#define N_FRAMES 16386
#define D_DIM    1024
#define O_DIM    2048
#define L_CTX    3
#define K_DIM    3072   // D_DIM * L_CTX
#define T_DIM    16384  // N_FRAMES - L_CTX + 1
#define NKT      24     // K_DIM / 128  (128-byte K-tiles)

// workspace byte offsets
#define WS_PART   0u        // 512 x uint2 flipped {min,max} partials
#define WS_PARAMS 8192u
#define WS_CO     16384u    // O_DIM int32
#define WS_S      32768u    // N_FRAMES int32
#define WS_QW     262144u
#define WS_QX     8388608u

struct Params {
  float w_scale, in_scale, cscale;
  int   w_zp, in_zp, konst;
};

typedef __attribute__((address_space(3))) void       lds_void;
typedef const __attribute__((address_space(1))) void gbl_void;

__device__ __forceinline__ unsigned flip_f(float f) {
  unsigned u = __float_as_uint(f);
  return (u & 0x80000000u) ? ~u : (u | 0x80000000u);
}
__device__ __forceinline__ float unflip_f(unsigned v) {
  unsigned u = (v & 0x80000000u) ? (v ^ 0x80000000u) : ~v;
  return __uint_as_float(u);
}

// grid must be exactly 512 blocks; block b writes partials[b] = {min,max} (flipped)
__global__ __launch_bounds__(256) void wminmax_kernel(const float4* __restrict__ w,
                                                      uint2* __restrict__ part, int n4) {
  unsigned lmin = 0xFFFFFFFFu, lmax = 0u;
  for (int i = blockIdx.x * blockDim.x + threadIdx.x; i < n4; i += gridDim.x * blockDim.x) {
    float4 v = w[i];
    unsigned a = flip_f(v.x), b = flip_f(v.y), c = flip_f(v.z), d = flip_f(v.w);
    lmin = min(lmin, min(min(a, b), min(c, d)));
    lmax = max(lmax, max(max(a, b), max(c, d)));
  }
#pragma unroll
  for (int off = 32; off > 0; off >>= 1) {
    lmin = min(lmin, (unsigned)__shfl_xor((int)lmin, off, 64));
    lmax = max(lmax, (unsigned)__shfl_xor((int)lmax, off, 64));
  }
  __shared__ unsigned rmn[4], rmx[4];
  const int wv = threadIdx.x >> 6;
  if ((threadIdx.x & 63) == 0) { rmn[wv] = lmin; rmx[wv] = lmax; }
  __syncthreads();
  if (threadIdx.x == 0) {
    unsigned mn = min(min(rmn[0], rmn[1]), min(rmn[2], rmn[3]));
    unsigned mx = max(max(rmx[0], rmx[1]), max(rmx[2], rmx[3]));
    part[blockIdx.x] = make_uint2(mn, mx);
  }
}

// reduce 512 partials -> Params
__global__ __launch_bounds__(256) void params_kernel(const uint2* __restrict__ part,
                                                     const float* __restrict__ in_min,
                                                     const float* __restrict__ in_max,
                                                     Params* __restrict__ p) {
  const int t = threadIdx.x;
  uint2 a = part[t], b = part[t + 256];
  unsigned mn = min(a.x, b.x), mx = max(a.y, b.y);
#pragma unroll
  for (int off = 32; off > 0; off >>= 1) {
    mn = min(mn, (unsigned)__shfl_xor((int)mn, off, 64));
    mx = max(mx, (unsigned)__shfl_xor((int)mx, off, 64));
  }
  __shared__ unsigned rmn[4], rmx[4];
  const int wv = t >> 6;
  if ((t & 63) == 0) { rmn[wv] = mn; rmx[wv] = mx; }
  __syncthreads();
  if (t == 0) {
    float wmin = unflip_f(min(min(rmn[0], rmn[1]), min(rmn[2], rmn[3])));
    float wmax = unflip_f(max(max(rmx[0], rmx[1]), max(rmx[2], rmx[3])));
    float ws = (wmax - wmin) / 254.0f;
    float wz = -127.0f - wmin / ws;
    wz = fminf(fmaxf(wz, -127.0f), 127.0f);
    int wzp = (int)wz;  // trunc toward zero, matches jnp.trunc->int
    float imin = *in_min, imax = *in_max;
    float is = (imax - imin) / 254.0f;
    float iz = -127.0f - imin / is;
    iz = fminf(fmaxf(iz, -127.0f), 127.0f);
    int izp = (int)iz;
    p->w_scale = ws; p->in_scale = is; p->cscale = is * ws;
    p->w_zp = wzp;   p->in_zp = izp;
    p->konst = K_DIM * wzp * izp;
  }
}

__global__ __launch_bounds__(256) void quantw_kernel(
    const float* __restrict__ w, const float* __restrict__ bias,
    const Params* __restrict__ p, int8_t* __restrict__ qw,
    int* __restrict__ co, float* __restrict__ dq, float* __restrict__ bias_out) {
  const int o = blockIdx.x;
  const float ws = p->w_scale;
  const float zpf = (float)p->w_zp;
  const float* wrow = w + (size_t)o * K_DIM;
  float* dqrow = dq + (size_t)o * K_DIM;
  int8_t* qrow = qw + (size_t)o * K_DIM;
  int sum = 0;
#pragma unroll
  for (int pass = 0; pass < 3; ++pass) {
    const int k = (pass << 10) + (threadIdx.x << 2);
    float4 v = *(const float4*)(wrow + k);
    int8_t c0 = (int8_t)(int)rintf(v.x / ws + zpf);
    int8_t c1 = (int8_t)(int)rintf(v.y / ws + zpf);
    int8_t c2 = (int8_t)(int)rintf(v.z / ws + zpf);
    int8_t c3 = (int8_t)(int)rintf(v.w / ws + zpf);
    sum += (int)c0 + (int)c1 + (int)c2 + (int)c3;
    unsigned packed = (unsigned)(uint8_t)c0 | ((unsigned)(uint8_t)c1 << 8)
                    | ((unsigned)(uint8_t)c2 << 16) | ((unsigned)(uint8_t)c3 << 24);
    *(unsigned*)(qrow + k) = packed;
    float4 d;
    d.x = ((float)c0 - zpf) * ws;
    d.y = ((float)c1 - zpf) * ws;
    d.z = ((float)c2 - zpf) * ws;
    d.w = ((float)c3 - zpf) * ws;
    *(float4*)(dqrow + k) = d;
  }
  __shared__ int red[4];
#pragma unroll
  for (int off = 32; off > 0; off >>= 1) sum += __shfl_xor(sum, off, 64);
  if ((threadIdx.x & 63) == 0) red[threadIdx.x >> 6] = sum;
  __syncthreads();
  if (threadIdx.x == 0) {
    int tot = red[0] + red[1] + red[2] + red[3];
    co[o] = -p->in_zp * tot;
    bias_out[o] = bias[o];
  }
}

__global__ __launch_bounds__(256) void quantx_kernel(
    const float* __restrict__ x, const Params* __restrict__ p,
    int8_t* __restrict__ qx, int* __restrict__ s) {
  const int n = blockIdx.x;
  const float is = p->in_scale;
  const float zpf = (float)p->in_zp;
  const float4 v = *((const float4*)(x + (size_t)n * D_DIM) + threadIdx.x);
  int8_t c0 = (int8_t)(int)rintf(v.x / is + zpf);
  int8_t c1 = (int8_t)(int)rintf(v.y / is + zpf);
  int8_t c2 = (int8_t)(int)rintf(v.z / is + zpf);
  int8_t c3 = (int8_t)(int)rintf(v.w / is + zpf);
  unsigned packed = (unsigned)(uint8_t)c0 | ((unsigned)(uint8_t)c1 << 8)
                  | ((unsigned)(uint8_t)c2 << 16) | ((unsigned)(uint8_t)c3 << 24);
  ((unsigned*)(qx + (size_t)n * D_DIM))[threadIdx.x] = packed;
  int sum = (int)c0 + (int)c1 + (int)c2 + (int)c3;
  __shared__ int red[4];
#pragma unroll
  for (int off = 32; off > 0; off >>= 1) sum += __shfl_xor(sum, off, 64);
  if ((threadIdx.x & 63) == 0) red[threadIdx.x >> 6] = sum;
  __syncthreads();
  if (threadIdx.x == 0) s[n] = red[0] + red[1] + red[2] + red[3];
}

// int8 NT GEMM, 256x256 tile, 128B K-tiles, 8 waves (R12 base + split-lgkm
// overlap). Per K-tile: {issue 12 ds_read ks1(kt) | lgkmcnt(12) [ks0 ready,
// ks1 fly] | 32 MFMA ks0 (covers ks1 reads) | lgkmcnt(0) | 32 MFMA ks1 |
// vmcnt(0) [own stage(kt+1)] | barrier [block-wide cert] |
// 12 ds_read ks0(kt+1) from nxt | stage(kt+2) -> buf}.
__global__ __launch_bounds__(512, 2) void gemm_kernel(
    const int8_t* __restrict__ qx, const int8_t* __restrict__ qw,
    const int* __restrict__ co, const int* __restrict__ s,
    const float* __restrict__ bias, const Params* __restrict__ p,
    float* __restrict__ out) {
  __shared__ int8_t A_lds[2][256 * 128];   // 32 KB per buf
  __shared__ int8_t B_lds[2][256 * 128];

  const int bid = blockIdx.x;
  const int tn = bid & 7;   // XCD-local n-tile: B panel L2-resident per XCD
  const int tm = bid >> 3;
  const int m0 = tm << 8, n0 = tn << 8;
  const int tid = threadIdx.x;
  const int lane = tid & 63, wave = tid >> 6;
  const int wm = wave >> 2, wn = wave & 3;   // 2x4 wave grid, per-wave 128x64
  const int lr = lane & 15, kg = lane >> 4;
  const int lr7 = lane & 7;

  // staging: thread t covers row t>>3, lds chunk t&7; source chunk pre-swizzled
  // with ^(row&7) so linear LDS dest holds swizzled layout.
  const int st_row = tid >> 3;
  const int st_sc  = ((tid & 7) ^ (st_row & 7)) << 4;
  const int8_t* qxa = qx + (size_t)(m0 + st_row) * D_DIM + st_sc;
  const int8_t* qwb = qw + (size_t)(n0 + st_row) * K_DIM + st_sc;

  // fragment read: phys chunk = ((ks<<2)|kg) ^ (row&7); row&7 == lr7
  const int c0 = (kg ^ lr7) << 4;            // ks=0; ks=1 -> c0 ^ 64
  const int arow = ((wm << 7) + lr) << 7;    // A row base byte
  const int brow = ((wn << 6) + lr) << 7;

  i32x4 a[8][2], b[4][2];
  i32x4 acc[8][4] = {};

  auto stageA = [&](int buf, int kt) {
    const int8_t* sp = qxa + (kt << 7);
#pragma unroll
    for (int j = 0; j < 4; ++j)
      __builtin_amdgcn_global_load_lds((gbl_void*)(sp + (size_t)(j << 6) * D_DIM),
          (lds_void*)(&A_lds[buf][(j << 13) + (wave << 10)]), 16, 0, 0);
  };
  auto stageB = [&](int buf, int kt) {
    const int8_t* sp = qwb + (kt << 7);
#pragma unroll
    for (int j = 0; j < 4; ++j)
      __builtin_amdgcn_global_load_lds((gbl_void*)(sp + (size_t)(j << 6) * K_DIM),
          (lds_void*)(&B_lds[buf][(j << 13) + (wave << 10)]), 16, 0, 0);
  };
  // 12 ds_read_b128 of one ks-half of the tile's fragments from LDS buffer bf
  auto read_half = [&](int bf, int ks) {
#pragma unroll
    for (int m = 0; m < 8; ++m)
      a[m][ks] = *(const i32x4*)&A_lds[bf][arow + (m << 11) + (c0 ^ (ks << 6))];
#pragma unroll
    for (int n = 0; n < 4; ++n)
      b[n][ks] = *(const i32x4*)&B_lds[bf][brow + (n << 11) + (c0 ^ (ks << 6))];
  };

  // prologue: stage tiles 0,1; wait tile 0 (tile 1's 8 loads stay in flight);
  // read ks=0 half of tile 0.
  stageA(0, 0); stageB(0, 0);
  stageA(1, 1); stageB(1, 1);
  asm volatile("s_waitcnt vmcnt(8)" ::: "memory");
  __builtin_amdgcn_s_barrier();
  read_half(0, 0);

  for (int kt = 0; kt < NKT; ++kt) {
    const int buf = kt & 1, nxt = buf ^ 1;

    // issue ks1 reads; gate only on the 12 ks0 reads (ks1 fly under MFMA ks0)
    read_half(buf, 1);
    asm volatile("s_waitcnt lgkmcnt(12)" ::: "memory");
    __builtin_amdgcn_s_setprio(1);
#pragma unroll
    for (int m = 0; m < 8; ++m)
#pragma unroll
      for (int n = 0; n < 4; ++n)
        acc[m][n] = __builtin_amdgcn_mfma_i32_16x16x64_i8(a[m][0], b[n][0], acc[m][n], 0, 0, 0);
    __builtin_amdgcn_s_setprio(0);
    asm volatile("s_waitcnt lgkmcnt(0)" ::: "memory");   // ks1 done (hidden under MFMA)
    __builtin_amdgcn_s_setprio(1);
#pragma unroll
    for (int m = 0; m < 8; ++m)
#pragma unroll
      for (int n = 0; n < 4; ++n)
        acc[m][n] = __builtin_amdgcn_mfma_i32_16x16x64_i8(a[m][1], b[n][1], acc[m][n], 0, 0, 0);
    __builtin_amdgcn_s_setprio(0);

    if (kt + 1 < NKT) {
      asm volatile("s_waitcnt vmcnt(0)" ::: "memory");   // own stage(kt+1) loads landed
      __builtin_amdgcn_s_barrier();                      // block-wide: stage(kt+1) landed
                                                         // AND all frags(kt) reads drained
      read_half(nxt, 0);                                 // ks0 of tile kt+1
      if (kt + 2 < NKT) { stageA(buf, kt + 2); stageB(buf, kt + 2); }  // buf certified free
    }
  }

  // epilogue: dequant + zero-point correction (ct inline from s[]) + bias
  const float cscale = p->cscale;
  const int   wzp    = p->w_zp;
  const int   konst  = p->konst;
  int   cov[4];
  float bov[4];
#pragma unroll
  for (int n = 0; n < 4; ++n) {
    const int o_ = n0 + (wn << 6) + (n << 4) + lr;
    cov[n] = co[o_];
    bov[n] = bias[o_];
  }
#pragma unroll
  for (int m = 0; m < 8; ++m) {
    const int tbase = m0 + (wm << 7) + (m << 4) + (kg << 2);
    int sv[6];
#pragma unroll
    for (int r = 0; r < 6; ++r) sv[r] = s[tbase + r];
    int ctv[4];
#pragma unroll
    for (int r = 0; r < 4; ++r) ctv[r] = konst - wzp * (sv[r] + sv[r + 1] + sv[r + 2]);
#pragma unroll
    for (int n = 0; n < 4; ++n) {
      const int o_ = n0 + (wn << 6) + (n << 4) + lr;
#pragma unroll
      for (int r = 0; r < 4; ++r) {
        out[(size_t)(tbase + r) * O_DIM + o_] =
            (float)(acc[m][n][r] + cov[n] + ctv[r]) * cscale + bov[n];
      }
    }
  }
}

extern "C" void kernel_launch(void* const* d_in, const int* in_sizes, int n_in,
                              void* d_out, int out_size, void* d_ws, size_t ws_size,
                              hipStream_t stream) {
  const float* x      = (const float*)d_in[0];
  const float* w      = (const float*)d_in[1];
  const float* bias   = (const float*)d_in[2];
  const float* in_min = (const float*)d_in[3];
  const float* in_max = (const float*)d_in[4];
  float* out = (float*)d_out;

  uint8_t* ws = (uint8_t*)d_ws;
  uint2*    part = (uint2*)(ws + WS_PART);
  Params*   prm  = (Params*)(ws + WS_PARAMS);
  int*      co   = (int*)(ws + WS_CO);
  int*      s    = (int*)(ws + WS_S);
  int8_t*   qw   = (int8_t*)(ws + WS_QW);
  int8_t*   qx   = (int8_t*)(ws + WS_QX);

  float* dq_out   = out + (size_t)T_DIM * O_DIM;
  float* bias_out = dq_out + (size_t)O_DIM * K_DIM;

  wminmax_kernel<<<512, 256, 0, stream>>>((const float4*)w, part, O_DIM * K_DIM / 4);
  params_kernel<<<1, 256, 0, stream>>>(part, in_min, in_max, prm);
  quantw_kernel<<<O_DIM, 256, 0, stream>>>(w, bias, prm, qw, co, dq_out, bias_out);
  quantx_kernel<<<N_FRAMES, 256, 0, stream>>>(x, prm, qx, s);
  gemm_kernel<<<(T_DIM / 256) * (O_DIM / 256), 512, 0, stream>>>(qx, qw, co, s, bias, prm, out);
}

// Round 15
// 135.852 us; speedup vs baseline: 1.1312x; 1.1028x over previous
//
#include <hip/hip_runtime.h>
#include <stdint.h>

typedef __attribute__((ext_vector_type(4))) int i32x4;

#define N_FRAMES 16386
#define D_DIM    1024
#define O_DIM    2048
#define L_CTX    3
#define K_DIM    3072   // D_DIM * L_CTX
#define T_DIM    16384  // N_FRAMES - L_CTX + 1
#define NKT      24     // K_DIM / 128  (128-byte K-tiles)

// workspace byte offsets
#define WS_PART   0u        // 512 x uint2 flipped {min,max} partials
#define WS_PARAMS 8192u
#define WS_CO     16384u    // O_DIM int32
#define WS_S      32768u    // N_FRAMES int32
#define WS_QW     262144u
#define WS_QX     8388608u

struct Params {
  float w_scale, in_scale, cscale;
  int   w_zp, in_zp, konst;
};

typedef __attribute__((address_space(3))) void       lds_void;
typedef const __attribute__((address_space(1))) void gbl_void;

__device__ __forceinline__ unsigned flip_f(float f) {
  unsigned u = __float_as_uint(f);
  return (u & 0x80000000u) ? ~u : (u | 0x80000000u);
}
__device__ __forceinline__ float unflip_f(unsigned v) {
  unsigned u = (v & 0x80000000u) ? (v ^ 0x80000000u) : ~v;
  return __uint_as_float(u);
}

// grid must be exactly 512 blocks; block b writes partials[b] = {min,max} (flipped)
__global__ __launch_bounds__(256) void wminmax_kernel(const float4* __restrict__ w,
                                                      uint2* __restrict__ part, int n4) {
  unsigned lmin = 0xFFFFFFFFu, lmax = 0u;
  for (int i = blockIdx.x * blockDim.x + threadIdx.x; i < n4; i += gridDim.x * blockDim.x) {
    float4 v = w[i];
    unsigned a = flip_f(v.x), b = flip_f(v.y), c = flip_f(v.z), d = flip_f(v.w);
    lmin = min(lmin, min(min(a, b), min(c, d)));
    lmax = max(lmax, max(max(a, b), max(c, d)));
  }
#pragma unroll
  for (int off = 32; off > 0; off >>= 1) {
    lmin = min(lmin, (unsigned)__shfl_xor((int)lmin, off, 64));
    lmax = max(lmax, (unsigned)__shfl_xor((int)lmax, off, 64));
  }
  __shared__ unsigned rmn[4], rmx[4];
  const int wv = threadIdx.x >> 6;
  if ((threadIdx.x & 63) == 0) { rmn[wv] = lmin; rmx[wv] = lmax; }
  __syncthreads();
  if (threadIdx.x == 0) {
    unsigned mn = min(min(rmn[0], rmn[1]), min(rmn[2], rmn[3]));
    unsigned mx = max(max(rmx[0], rmx[1]), max(rmx[2], rmx[3]));
    part[blockIdx.x] = make_uint2(mn, mx);
  }
}

// reduce 512 partials -> Params
__global__ __launch_bounds__(256) void params_kernel(const uint2* __restrict__ part,
                                                     const float* __restrict__ in_min,
                                                     const float* __restrict__ in_max,
                                                     Params* __restrict__ p) {
  const int t = threadIdx.x;
  uint2 a = part[t], b = part[t + 256];
  unsigned mn = min(a.x, b.x), mx = max(a.y, b.y);
#pragma unroll
  for (int off = 32; off > 0; off >>= 1) {
    mn = min(mn, (unsigned)__shfl_xor((int)mn, off, 64));
    mx = max(mx, (unsigned)__shfl_xor((int)mx, off, 64));
  }
  __shared__ unsigned rmn[4], rmx[4];
  const int wv = t >> 6;
  if ((t & 63) == 0) { rmn[wv] = mn; rmx[wv] = mx; }
  __syncthreads();
  if (t == 0) {
    float wmin = unflip_f(min(min(rmn[0], rmn[1]), min(rmn[2], rmn[3])));
    float wmax = unflip_f(max(max(rmx[0], rmx[1]), max(rmx[2], rmx[3])));
    float ws = (wmax - wmin) / 254.0f;
    float wz = -127.0f - wmin / ws;
    wz = fminf(fmaxf(wz, -127.0f), 127.0f);
    int wzp = (int)wz;  // trunc toward zero, matches jnp.trunc->int
    float imin = *in_min, imax = *in_max;
    float is = (imax - imin) / 254.0f;
    float iz = -127.0f - imin / is;
    iz = fminf(fmaxf(iz, -127.0f), 127.0f);
    int izp = (int)iz;
    p->w_scale = ws; p->in_scale = is; p->cscale = is * ws;
    p->w_zp = wzp;   p->in_zp = izp;
    p->konst = K_DIM * wzp * izp;
  }
}

__global__ __launch_bounds__(256) void quantw_kernel(
    const float* __restrict__ w, const float* __restrict__ bias,
    const Params* __restrict__ p, int8_t* __restrict__ qw,
    int* __restrict__ co, float* __restrict__ dq, float* __restrict__ bias_out) {
  const int o = blockIdx.x;
  const float ws = p->w_scale;
  const float zpf = (float)p->w_zp;
  const float* wrow = w + (size_t)o * K_DIM;
  float* dqrow = dq + (size_t)o * K_DIM;
  int8_t* qrow = qw + (size_t)o * K_DIM;
  int sum = 0;
#pragma unroll
  for (int pass = 0; pass < 3; ++pass) {
    const int k = (pass << 10) + (threadIdx.x << 2);
    float4 v = *(const float4*)(wrow + k);
    int8_t c0 = (int8_t)(int)rintf(v.x / ws + zpf);
    int8_t c1 = (int8_t)(int)rintf(v.y / ws + zpf);
    int8_t c2 = (int8_t)(int)rintf(v.z / ws + zpf);
    int8_t c3 = (int8_t)(int)rintf(v.w / ws + zpf);
    sum += (int)c0 + (int)c1 + (int)c2 + (int)c3;
    unsigned packed = (unsigned)(uint8_t)c0 | ((unsigned)(uint8_t)c1 << 8)
                    | ((unsigned)(uint8_t)c2 << 16) | ((unsigned)(uint8_t)c3 << 24);
    *(unsigned*)(qrow + k) = packed;
    float4 d;
    d.x = ((float)c0 - zpf) * ws;
    d.y = ((float)c1 - zpf) * ws;
    d.z = ((float)c2 - zpf) * ws;
    d.w = ((float)c3 - zpf) * ws;
    *(float4*)(dqrow + k) = d;
  }
  __shared__ int red[4];
#pragma unroll
  for (int off = 32; off > 0; off >>= 1) sum += __shfl_xor(sum, off, 64);
  if ((threadIdx.x & 63) == 0) red[threadIdx.x >> 6] = sum;
  __syncthreads();
  if (threadIdx.x == 0) {
    int tot = red[0] + red[1] + red[2] + red[3];
    co[o] = -p->in_zp * tot;
    bias_out[o] = bias[o];
  }
}

__global__ __launch_bounds__(256) void quantx_kernel(
    const float* __restrict__ x, const Params* __restrict__ p,
    int8_t* __restrict__ qx, int* __restrict__ s) {
  const int n = blockIdx.x;
  const float is = p->in_scale;
  const float zpf = (float)p->in_zp;
  const float4 v = *((const float4*)(x + (size_t)n * D_DIM) + threadIdx.x);
  int8_t c0 = (int8_t)(int)rintf(v.x / is + zpf);
  int8_t c1 = (int8_t)(int)rintf(v.y / is + zpf);
  int8_t c2 = (int8_t)(int)rintf(v.z / is + zpf);
  int8_t c3 = (int8_t)(int)rintf(v.w / is + zpf);
  unsigned packed = (unsigned)(uint8_t)c0 | ((unsigned)(uint8_t)c1 << 8)
                  | ((unsigned)(uint8_t)c2 << 16) | ((unsigned)(uint8_t)c3 << 24);
  ((unsigned*)(qx + (size_t)n * D_DIM))[threadIdx.x] = packed;
  int sum = (int)c0 + (int)c1 + (int)c2 + (int)c3;
  __shared__ int red[4];
#pragma unroll
  for (int off = 32; off > 0; off >>= 1) sum += __shfl_xor(sum, off, 64);
  if ((threadIdx.x & 63) == 0) red[threadIdx.x >> 6] = sum;
  __syncthreads();
  if (threadIdx.x == 0) s[n] = red[0] + red[1] + red[2] + red[3];
}

// int8 NT GEMM, 256x256 tile, 128B K-tiles, 8 waves.
// ONE-phase K-tile, barrier-certified (R12 — empirical optimum):
//  {lgkmcnt(0) [frags(kt) done] | setprio | 64 MFMA | setprio |
//   vmcnt(0) [own stage(kt+1) landed] |
//   s_barrier [block-wide: stage(kt+1) landed AND frags(kt) reads drained] |
//   24 ds_read frags(kt+1) from nxt | stage(kt+2) -> buf}.
// 1 barrier + 1 vmcnt + 1 lgkm per K-tile.
__global__ __launch_bounds__(512, 2) void gemm_kernel(
    const int8_t* __restrict__ qx, const int8_t* __restrict__ qw,
    const int* __restrict__ co, const int* __restrict__ s,
    const float* __restrict__ bias, const Params* __restrict__ p,
    float* __restrict__ out) {
  __shared__ int8_t A_lds[2][256 * 128];   // 32 KB per buf
  __shared__ int8_t B_lds[2][256 * 128];

  const int bid = blockIdx.x;
  const int tn = bid & 7;   // XCD-local n-tile: B panel L2-resident per XCD
  const int tm = bid >> 3;
  const int m0 = tm << 8, n0 = tn << 8;
  const int tid = threadIdx.x;
  const int lane = tid & 63, wave = tid >> 6;
  const int wm = wave >> 2, wn = wave & 3;   // 2x4 wave grid, per-wave 128x64
  const int lr = lane & 15, kg = lane >> 4;
  const int lr7 = lane & 7;

  // staging: thread t covers row t>>3, lds chunk t&7; source chunk pre-swizzled
  // with ^(row&7) so linear LDS dest holds swizzled layout.
  const int st_row = tid >> 3;
  const int st_sc  = ((tid & 7) ^ (st_row & 7)) << 4;
  const int8_t* qxa = qx + (size_t)(m0 + st_row) * D_DIM + st_sc;
  const int8_t* qwb = qw + (size_t)(n0 + st_row) * K_DIM + st_sc;

  // fragment read: phys chunk = ((ks<<2)|kg) ^ (row&7); row&7 == lr7
  const int c0 = (kg ^ lr7) << 4;            // ks=0; ks=1 -> c0 ^ 64
  const int arow = ((wm << 7) + lr) << 7;    // A row base byte
  const int brow = ((wn << 6) + lr) << 7;

  i32x4 a[8][2], b[4][2];
  i32x4 acc[8][4] = {};

  auto stageA = [&](int buf, int kt) {
    const int8_t* sp = qxa + (kt << 7);
#pragma unroll
    for (int j = 0; j < 4; ++j)
      __builtin_amdgcn_global_load_lds((gbl_void*)(sp + (size_t)(j << 6) * D_DIM),
          (lds_void*)(&A_lds[buf][(j << 13) + (wave << 10)]), 16, 0, 0);
  };
  auto stageB = [&](int buf, int kt) {
    const int8_t* sp = qwb + (kt << 7);
#pragma unroll
    for (int j = 0; j < 4; ++j)
      __builtin_amdgcn_global_load_lds((gbl_void*)(sp + (size_t)(j << 6) * K_DIM),
          (lds_void*)(&B_lds[buf][(j << 13) + (wave << 10)]), 16, 0, 0);
  };
  // 24 ds_read_b128: full fragment set for the tile in LDS buffer bf
  auto read_full = [&](int bf) {
#pragma unroll
    for (int ks = 0; ks < 2; ++ks) {
#pragma unroll
      for (int m = 0; m < 8; ++m)
        a[m][ks] = *(const i32x4*)&A_lds[bf][arow + (m << 11) + (c0 ^ (ks << 6))];
#pragma unroll
      for (int n = 0; n < 4; ++n)
        b[n][ks] = *(const i32x4*)&B_lds[bf][brow + (n << 11) + (c0 ^ (ks << 6))];
    }
  };

  // prologue: stage tiles 0,1; wait tile 0 (tile 1's 8 loads stay in flight);
  // read full fragment set of tile 0.
  stageA(0, 0); stageB(0, 0);
  stageA(1, 1); stageB(1, 1);
  asm volatile("s_waitcnt vmcnt(8)" ::: "memory");
  __builtin_amdgcn_s_barrier();
  read_full(0);

  for (int kt = 0; kt < NKT; ++kt) {
    const int buf = kt & 1, nxt = buf ^ 1;

    asm volatile("s_waitcnt lgkmcnt(0)" ::: "memory");   // frags(kt) complete (own reads)
    __builtin_amdgcn_s_setprio(1);
#pragma unroll
    for (int m = 0; m < 8; ++m)
#pragma unroll
      for (int n = 0; n < 4; ++n)
#pragma unroll
        for (int ks = 0; ks < 2; ++ks)
          acc[m][n] = __builtin_amdgcn_mfma_i32_16x16x64_i8(a[m][ks], b[n][ks], acc[m][n], 0, 0, 0);
    __builtin_amdgcn_s_setprio(0);

    if (kt + 1 < NKT) {
      asm volatile("s_waitcnt vmcnt(0)" ::: "memory");   // own stage(kt+1) loads landed
      __builtin_amdgcn_s_barrier();                      // block-wide: stage(kt+1) landed
                                                         // AND all frags(kt) reads drained
      read_full(nxt);                                    // tile kt+1; gated next iter
      if (kt + 2 < NKT) { stageA(buf, kt + 2); stageB(buf, kt + 2); }  // buf certified free
    }
  }

  // epilogue: dequant + zero-point correction (ct inline from s[]) + bias
  const float cscale = p->cscale;
  const int   wzp    = p->w_zp;
  const int   konst  = p->konst;
  int   cov[4];
  float bov[4];
#pragma unroll
  for (int n = 0; n < 4; ++n) {
    const int o_ = n0 + (wn << 6) + (n << 4) + lr;
    cov[n] = co[o_];
    bov[n] = bias[o_];
  }
#pragma unroll
  for (int m = 0; m < 8; ++m) {
    const int tbase = m0 + (wm << 7) + (m << 4) + (kg << 2);
    int sv[6];
#pragma unroll
    for (int r = 0; r < 6; ++r) sv[r] = s[tbase + r];
    int ctv[4];
#pragma unroll
    for (int r = 0; r < 4; ++r) ctv[r] = konst - wzp * (sv[r] + sv[r + 1] + sv[r + 2]);
#pragma unroll
    for (int n = 0; n < 4; ++n) {
      const int o_ = n0 + (wn << 6) + (n << 4) + lr;
#pragma unroll
      for (int r = 0; r < 4; ++r) {
        out[(size_t)(tbase + r) * O_DIM + o_] =
            (float)(acc[m][n][r] + cov[n] + ctv[r]) * cscale + bov[n];
      }
    }
  }
}

extern "C" void kernel_launch(void* const* d_in, const int* in_sizes, int n_in,
                              void* d_out, int out_size, void* d_ws, size_t ws_size,
                              hipStream_t stream) {
  const float* x      = (const float*)d_in[0];
  const float* w      = (const float*)d_in[1];
  const float* bias   = (const float*)d_in[2];
  const float* in_min = (const float*)d_in[3];
  const float* in_max = (const float*)d_in[4];
  float* out = (float*)d_out;

  uint8_t* ws = (uint8_t*)d_ws;
  uint2*    part = (uint2*)(ws + WS_PART);
  Params*   prm  = (Params*)(ws + WS_PARAMS);
  int*      co   = (int*)(ws + WS_CO);
  int*      s    = (int*)(ws + WS_S);
  int8_t*   qw   = (int8_t*)(ws + WS_QW);
  int8_t*   qx   = (int8_t*)(ws + WS_QX);

  float* dq_out   = out + (size_t)T_DIM * O_DIM;
  float* bias_out = dq_out + (size_t)O_DIM * K_DIM;

  wminmax_kernel<<<512, 256, 0, stream>>>((const float4*)w, part, O_DIM * K_DIM / 4);
  params_kernel<<<1, 256, 0, stream>>>(part, in_min, in_max, prm);
  quantw_kernel<<<O_DIM, 256, 0, stream>>>(w, bias, prm, qw, co, dq_out, bias_out);
  quantx_kernel<<<N_FRAMES, 256, 0, stream>>>(x, prm, qx, s);
  gemm_kernel<<<(T_DIM / 256) * (O_DIM / 256), 512, 0, stream>>>(qx, qw, co, s, bias, prm, out);
}